// Round 1
// 638.926 us; speedup vs baseline: 1.2720x; 1.2720x over previous
//
#include <hip/hip_runtime.h>
#include <math.h>

typedef unsigned long long ull;
typedef __attribute__((ext_vector_type(2))) ull ullx2;
typedef __attribute__((ext_vector_type(2))) int intx2;
typedef __attribute__((ext_vector_type(4))) unsigned uintx4;
typedef __attribute__((ext_vector_type(2))) float floatx2;
typedef __attribute__((ext_vector_type(4))) float floatx4;

static constexpr int R = 1000;
static constexpr int D = 100;
static constexpr int M = 2000000;
static constexpr int B = 8;            // edges/thread in k_norm
static constexpr int NB = 128;         // receiver buckets (sort path)
static constexpr int BBITS = 14;       // bins per bucket = 16384
static constexpr int BINS = 1 << BBITS;
static constexpr int EPB = 4096;       // edges per block in k_gate_sort
static constexpr int BT = 16;          // edges per thread in k_gate_sort
static constexpr int NSUB = 4;         // segment-split factor for k_acc
static constexpr int REP_WORDS = M / 2;  // fallback replica: 2 x16-bit bins/u32
static constexpr float QSCALE = 1024.0f;
static constexpr float INV_QSCALE = 1.0f / 1024.0f;

// ---------------------------------------------------------------------------
// K0: detect index dtype (int64 => high words of first 64 values are all 0).
__global__ __launch_bounds__(64) void k_detect(const unsigned int* __restrict__ words,
                                               int* __restrict__ flag) {
    int t = threadIdx.x;
    unsigned int v = words[2 * t + 1];
    unsigned long long m = __ballot(v != 0u);
    if (t == 0) *flag = (m == 0ull) ? 1 : 0;
}

// ---------------------------------------------------------------------------
// K1: table = sigmoid(G_sender @ G_receiver^T), 1000x1000.
__global__ __launch_bounds__(256) void k_table(const float* __restrict__ Gs,
                                               const float* __restrict__ Gr,
                                               float* __restrict__ table) {
    __shared__ float As[64][D + 1];
    __shared__ float Bs[64][D + 1];
    const int bx = blockIdx.x, by = blockIdx.y;
    const int t = threadIdx.x;
    for (int i = t; i < 64 * D; i += 256) {
        int row = i / D, col = i - row * D;
        int ga = by * 64 + row;
        As[row][col] = (ga < R) ? Gs[ga * D + col] : 0.f;
        int gb = bx * 64 + row;
        Bs[row][col] = (gb < R) ? Gr[gb * D + col] : 0.f;
    }
    __syncthreads();
    const int ty = t >> 4, tx = t & 15;
    float acc[4][4];
#pragma unroll
    for (int i = 0; i < 4; i++)
#pragma unroll
        for (int j = 0; j < 4; j++) acc[i][j] = 0.f;
    for (int k = 0; k < D; k++) {
        float a[4], b[4];
#pragma unroll
        for (int i = 0; i < 4; i++) a[i] = As[4 * ty + i][k];
#pragma unroll
        for (int j = 0; j < 4; j++) b[j] = Bs[4 * tx + j][k];
#pragma unroll
        for (int i = 0; i < 4; i++)
#pragma unroll
            for (int j = 0; j < 4; j++) acc[i][j] += a[i] * b[j];
    }
#pragma unroll
    for (int i = 0; i < 4; i++) {
        int row = by * 64 + 4 * ty + i;
        if (row >= R) continue;
#pragma unroll
        for (int j = 0; j < 4; j++) {
            int col = bx * 64 + 4 * tx + j;
            if (col < R) table[row * R + col] = 1.0f / (1.0f + expf(-acc[i][j]));
        }
    }
}

// ---------------------------------------------------------------------------
// SORT PATH ------------------------------------------------------------------
// K3s: per 4096-edge block: gather gates, write out/recv32, LDS multisplit by
// bucket=rv>>14, write bucket-sorted records + per-block packed offset row
// offtab[blk*NB + b] = off | (end << 16). No global atomics; deterministic.
// Record = (rv << 11) | qgate  (rv < 2^21, qgate <= 1024 < 2^11).
__global__ __launch_bounds__(256) void k_gate_sort(
    const void* __restrict__ rel, const void* __restrict__ pairs,
    const float* __restrict__ table, const int* __restrict__ flag,
    float* __restrict__ gates, int* __restrict__ recv32,
    unsigned* __restrict__ records, unsigned* __restrict__ offtab,
    int E, int store_recv) {
    __shared__ unsigned cnt[NB];
    __shared__ unsigned cursor[NB];
    __shared__ unsigned stage[EPB];
    __shared__ unsigned sh_carry, sh_total;
    const int tid = threadIdx.x;
    const int blk = blockIdx.x;
    const int base = blk * EPB;
    if (tid < NB) cnt[tid] = 0;
    __syncthreads();

    const bool is64 = (*flag != 0);
    unsigned rec[BT];
#pragma unroll
    for (int k = 0; k < BT; k++) rec[k] = 0xFFFFFFFFu;  // invalid marker
    // Phase 0: load indices (nt), gather table, write gates/recv, LDS count.
#pragma unroll
    for (int k = 0; k < BT; k++) {
        int e = base + k * 256 + tid;
        if (e < E) {
            int s, r, rv;
            if (is64) {
                ullx2 a = __builtin_nontemporal_load((const ullx2*)rel + e);
                ull b = __builtin_nontemporal_load((const ull*)pairs + 2 * e + 1);
                s = (int)a.x; r = (int)a.y; rv = (int)b;
            } else {
                intx2 a = __builtin_nontemporal_load((const intx2*)rel + e);
                int b = __builtin_nontemporal_load((const int*)pairs + 2 * e + 1);
                s = a.x; r = a.y; rv = b;
            }
            float g = table[s * R + r];
            __builtin_nontemporal_store(g, gates + e);
            if (store_recv) __builtin_nontemporal_store(rv, recv32 + e);
            unsigned q = (unsigned)(g * QSCALE + 0.5f);
            rec[k] = ((unsigned)rv << 11) | q;
            atomicAdd(&cnt[(unsigned)rv >> BBITS], 1u);
        }
    }
    __syncthreads();
    // Scan 128 counts: per-wave shfl inclusive scan + carry.
    unsigned c = 0, inc = 0;
    if (tid < NB) {
        c = cnt[tid];
        inc = c;
#pragma unroll
        for (int d = 1; d < 64; d <<= 1) {
            unsigned n = __shfl_up(inc, d, 64);
            if ((tid & 63) >= d) inc += n;
        }
        if (tid == 63) sh_carry = inc;
    }
    __syncthreads();
    if (tid < NB) {
        if (tid >= 64) inc += sh_carry;
        unsigned exc = inc - c;
        cursor[tid] = exc;
        offtab[(size_t)blk * NB + tid] = exc | (inc << 16);
        if (tid == NB - 1) sh_total = inc;
    }
    __syncthreads();
    // Phase C: place records bucket-sorted into LDS staging.
#pragma unroll
    for (int k = 0; k < BT; k++) {
        if (rec[k] != 0xFFFFFFFFu) {
            unsigned b = rec[k] >> (11 + BBITS);
            unsigned pos = atomicAdd(&cursor[b], 1u);
            stage[pos] = rec[k];
        }
    }
    __syncthreads();
    // Phase D: coalesced flush to this block's global segment.
    unsigned total = sh_total;
    for (unsigned i = tid; i < total; i += 256)
        __builtin_nontemporal_store(stage[i], records + (size_t)blk * EPB + i);
}

// K4s: nsub blocks per bucket (blockIdx = sub*NB + b); each handles a
// contiguous chunk of block-segments. Half-wave (32 lanes) per segment —
// matches avg run length 32. Packed offtab word prefetched one iteration
// ahead so the steady-state chain is one records-load per segment.
// nsub==1: write inv directly. nsub>1: deterministic u32 atomic flush to
// gbins; k_inv finalizes.
__global__ __launch_bounds__(1024) void k_acc(const unsigned* __restrict__ records,
                                              const unsigned* __restrict__ offtab,
                                              float* __restrict__ inv,
                                              unsigned* __restrict__ gbins,
                                              int nblk, int nsub) {
    __shared__ unsigned bins[BINS];  // 64 KB -> 2 blocks/CU
    const int b = blockIdx.x & (NB - 1);
    const int sub = blockIdx.x >> 7;  // NB == 128
    for (int i = threadIdx.x; i < BINS; i += 1024) bins[i] = 0;
    __syncthreads();
    const int hw = threadIdx.x >> 5;   // 32 half-wave streams per block
    const int lane = threadIdx.x & 31;
    const int chunk = (nblk + nsub - 1) / nsub;
    const int s0 = sub * chunk;
    const int s1 = min(nblk, s0 + chunk);
    int s = s0 + hw;
    unsigned ot_next = (s < s1) ? offtab[(size_t)s * NB + b] : 0u;
    for (; s < s1; s += 32) {
        unsigned ot = ot_next;
        int sn = s + 32;
        if (sn < s1) ot_next = offtab[(size_t)sn * NB + b];  // prefetch, hides
        unsigned off = ot & 0xFFFFu;
        unsigned end = ot >> 16;
        const unsigned* seg = records + (size_t)s * EPB;
        for (unsigned j = off + lane; j < end; j += 32) {
            unsigned r2 = __builtin_nontemporal_load(seg + j);
            atomicAdd(&bins[(r2 >> 11) & (BINS - 1)], r2 & 2047u);
        }
    }
    __syncthreads();
    const int mbase = b << BBITS;
    if (nsub == 1) {
        for (int i = threadIdx.x; i < BINS; i += 1024) {
            int m = mbase + i;
            if (m < M) inv[m] = 1.0f / ((float)bins[i] * INV_QSCALE + 1e-8f);
        }
    } else {
        for (int i = threadIdx.x; i < BINS; i += 1024) {
            unsigned v = bins[i];
            int m = mbase + i;
            if (v && m < M)
                __hip_atomic_fetch_add(&gbins[m], v, __ATOMIC_RELAXED,
                                       __HIP_MEMORY_SCOPE_AGENT);
        }
    }
}

// K4b: gbins (u32 quantized sums) -> inv reciprocals, 4-wide.
__global__ __launch_bounds__(256) void k_inv(const uintx4* __restrict__ gb,
                                             float* __restrict__ inv) {
    int i = blockIdx.x * 256 + threadIdx.x;
    if (i >= M / 4) return;
    uintx4 t = gb[i];
    floatx4 o;
    o.x = 1.0f / ((float)t.x * INV_QSCALE + 1e-8f);
    o.y = 1.0f / ((float)t.y * INV_QSCALE + 1e-8f);
    o.z = 1.0f / ((float)t.z * INV_QSCALE + 1e-8f);
    o.w = 1.0f / ((float)t.w * INV_QSCALE + 1e-8f);
    ((floatx4*)inv)[i] = o;
}

// ---------------------------------------------------------------------------
// FALLBACK PATH (small ws): round-4 atomic scheme -----------------------------
__global__ __launch_bounds__(256) void k_zero4(uintx4* __restrict__ p, int n4) {
    int i = blockIdx.x * 256 + threadIdx.x;
    if (i < n4) {
        uintx4 z = {0u, 0u, 0u, 0u};
        p[i] = z;
    }
}

__global__ __launch_bounds__(256) void k_gate_atomic(
    const void* __restrict__ rel, const void* __restrict__ pairs,
    const float* __restrict__ table, const int* __restrict__ flag,
    float* __restrict__ gates, int* __restrict__ recv32,
    unsigned* __restrict__ reps, int E, int store_recv) {
    const int tid = blockIdx.x * 256 + threadIdx.x;
    const int T = gridDim.x * 256;
    const bool is64 = (*flag != 0);
#pragma unroll
    for (int k = 0; k < B; k++) {
        int e = tid + k * T;
        if (e < E) {
            int s, r, rv;
            if (is64) {
                ullx2 a = __builtin_nontemporal_load((const ullx2*)rel + e);
                ull b = __builtin_nontemporal_load((const ull*)pairs + 2 * e + 1);
                s = (int)a.x; r = (int)a.y; rv = (int)b;
            } else {
                intx2 a = __builtin_nontemporal_load((const intx2*)rel + e);
                int b = __builtin_nontemporal_load((const int*)pairs + 2 * e + 1);
                s = a.x; r = a.y; rv = b;
            }
            float g = table[s * R + r];
            __builtin_nontemporal_store(g, gates + e);
            if (store_recv) __builtin_nontemporal_store(rv, recv32 + e);
            unsigned q = (unsigned)(g * QSCALE + 0.5f);
            unsigned addend = q << ((rv & 1) << 4);
            __hip_atomic_fetch_add(&reps[rv >> 1], addend, __ATOMIC_RELAXED,
                                   __HIP_MEMORY_SCOPE_AGENT);
        }
    }
}

__global__ __launch_bounds__(256) void k_merge(const unsigned* __restrict__ reps,
                                               float* __restrict__ inv) {
    int i = blockIdx.x * 256 + threadIdx.x;
    if (i >= REP_WORDS) return;
    unsigned t = reps[i];
    floatx2 o;
    o.x = 1.0f / ((float)(t & 0xFFFFu) * INV_QSCALE + 1e-8f);
    o.y = 1.0f / ((float)(t >> 16) * INV_QSCALE + 1e-8f);
    ((floatx2*)inv)[i] = o;
}

// ---------------------------------------------------------------------------
// K5: out[e] = gate[e] * inv_denom[recv[e]], B=8 ILP, nt streams.
__global__ __launch_bounds__(256) void k_norm(const int* __restrict__ recv32,
                                              const void* __restrict__ pairs,
                                              const int* __restrict__ flag,
                                              const float* __restrict__ inv,
                                              float* __restrict__ out, int E,
                                              int use_recv) {
    const int tid = blockIdx.x * 256 + threadIdx.x;
    const int T = gridDim.x * 256;
    int rv[B];
#pragma unroll
    for (int k = 0; k < B; k++) rv[k] = 0;
    if (use_recv) {
#pragma unroll
        for (int k = 0; k < B; k++) {
            int e = tid + k * T;
            if (e < E) rv[k] = __builtin_nontemporal_load(recv32 + e);
        }
    } else if (*flag) {
#pragma unroll
        for (int k = 0; k < B; k++) {
            int e = tid + k * T;
            if (e < E) rv[k] = (int)__builtin_nontemporal_load((const ull*)pairs + 2 * e + 1);
        }
    } else {
#pragma unroll
        for (int k = 0; k < B; k++) {
            int e = tid + k * T;
            if (e < E) rv[k] = __builtin_nontemporal_load((const int*)pairs + 2 * e + 1);
        }
    }
    float iv[B], gv[B];
#pragma unroll
    for (int k = 0; k < B; k++) {
        int e = tid + k * T;
        if (e < E) {
            iv[k] = inv[rv[k]];
            gv[k] = __builtin_nontemporal_load(out + e);
        }
    }
#pragma unroll
    for (int k = 0; k < B; k++) {
        int e = tid + k * T;
        if (e < E) __builtin_nontemporal_store(gv[k] * iv[k], out + e);
    }
}

// ---------------------------------------------------------------------------
extern "C" void kernel_launch(void* const* d_in, const int* in_sizes, int n_in,
                              void* d_out, int out_size, void* d_ws, size_t ws_size,
                              hipStream_t stream) {
    const float* Gs = (const float*)d_in[0];
    const float* Gr = (const float*)d_in[1];
    const void* rel = d_in[2];
    const void* pairs = d_in[3];
    float* out = (float*)d_out;
    const int E = out_size;  // 16,000,000
    const int nblk = (E + EPB - 1) / EPB;

    // Workspace layout:
    //   flag    [0, 4)
    //   table   [4 KiB, +4 MiB)
    //   inv     [+4 MiB, +8 MiB)
    //   offtab  [+8 MiB, 4 MiB reserved)   nblk*NB u32 packed (~2 MiB)
    //   records [+4 MiB, nblk*EPB*4)       (~64 MB)  [sort path]
    //   recv32  [after records, 4*E)
    //   gbins   [after recv32, 4*M)        (~8 MB)   [k_acc split merge]
    char* ws = (char*)d_ws;
    int* flag = (int*)ws;
    size_t off_table = 4096;
    size_t off_inv = off_table + ((size_t)4 << 20);
    size_t off_off = off_inv + ((size_t)8 << 20);
    size_t off_recs = off_off + ((size_t)4 << 20);
    size_t off_recv = off_recs + (size_t)nblk * EPB * 4;
    float* table = (float*)(ws + off_table);
    float* inv = (float*)(ws + off_inv);
    unsigned* offtab = (unsigned*)(ws + off_off);
    unsigned* records = (unsigned*)(ws + off_recs);
    int* recv32 = (int*)(ws + off_recv);

    const int sort_ok = (ws_size >= off_recv) ? 1 : 0;
    const int store_recv = (ws_size >= off_recv + (size_t)E * 4) ? 1 : 0;
    size_t off_gb = off_recv + (store_recv ? (size_t)E * 4 : 0);
    const int have_gb = (ws_size >= off_gb + (size_t)M * 4) ? 1 : 0;
    unsigned* gbins = (unsigned*)(ws + off_gb);

    k_detect<<<1, 64, 0, stream>>>((const unsigned int*)rel, flag);

    dim3 gt(16, 16);
    k_table<<<gt, 256, 0, stream>>>(Gs, Gr, table);

    if (sort_ok) {
        if (have_gb)
            k_zero4<<<(M / 4 + 255) / 256, 256, 0, stream>>>((uintx4*)gbins, M / 4);
        k_gate_sort<<<nblk, 256, 0, stream>>>(rel, pairs, table, flag, out, recv32,
                                              records, offtab, E, store_recv);
        const int S = have_gb ? NSUB : 1;
        k_acc<<<NB * S, 1024, 0, stream>>>(records, offtab, inv, gbins, nblk, S);
        if (have_gb)
            k_inv<<<(M / 4 + 255) / 256, 256, 0, stream>>>((const uintx4*)gbins, inv);
    } else {
        // Fallback: single-replica 16-bit global atomics (round-4 scheme).
        unsigned* reps = (unsigned*)(ws + off_off);
        k_zero4<<<(REP_WORDS / 4 + 255) / 256, 256, 0, stream>>>((uintx4*)reps,
                                                                 REP_WORDS / 4);
        const int eb = (E + 256 * B - 1) / (256 * B);
        k_gate_atomic<<<eb, 256, 0, stream>>>(rel, pairs, table, flag, out, recv32,
                                              reps, E, /*store_recv=*/0);
        k_merge<<<(REP_WORDS + 255) / 256, 256, 0, stream>>>(reps, inv);
    }

    const int eb = (E + 256 * B - 1) / (256 * B);
    const int use_recv = sort_ok ? store_recv : 0;
    k_norm<<<eb, 256, 0, stream>>>(recv32, pairs, flag, inv, out, E, use_recv);
}

// Round 2
// 597.207 us; speedup vs baseline: 1.3609x; 1.0699x over previous
//
#include <hip/hip_runtime.h>
#include <math.h>

typedef unsigned long long ull;
typedef __attribute__((ext_vector_type(2))) ull ullx2;
typedef __attribute__((ext_vector_type(2))) int intx2;
typedef __attribute__((ext_vector_type(4))) int intx4;
typedef __attribute__((ext_vector_type(4))) unsigned uintx4;
typedef __attribute__((ext_vector_type(2))) float floatx2;
typedef __attribute__((ext_vector_type(4))) float floatx4;

static constexpr int R = 1000;
static constexpr int D = 100;
static constexpr int M = 2000000;
static constexpr int NB = 128;         // receiver buckets (sort path)
static constexpr int BBITS = 14;       // bins per bucket = 16384
static constexpr int BINS = 1 << BBITS;
static constexpr int EPB = 4096;       // edges per block in k_gate_sort
static constexpr int GST = 512;        // threads in k_gate_sort
static constexpr int BT = EPB / GST;   // 8 edges per thread in k_gate_sort
static constexpr int NSUB = 4;         // segment-split factor for k_acc
static constexpr int NBV = 16;         // edges/thread in k_norm (x4 path)
static constexpr int BF = 8;           // edges/thread fallback kernels
static constexpr int REP_WORDS = M / 2;  // fallback replica: 2 x16-bit bins/u32
static constexpr float QSCALE = 1024.0f;
static constexpr float INV_QSCALE = 1.0f / 1024.0f;

// ---------------------------------------------------------------------------
// K1: table = sigmoid(G_sender @ G_receiver^T), 1000x1000.
// Fused: block (0,0) also detects index dtype (int64 => high words zero).
__global__ __launch_bounds__(256) void k_table(const float* __restrict__ Gs,
                                               const float* __restrict__ Gr,
                                               float* __restrict__ table,
                                               const unsigned* __restrict__ relw,
                                               int* __restrict__ flag) {
    const int bx = blockIdx.x, by = blockIdx.y;
    const int t = threadIdx.x;
    if (bx == 0 && by == 0 && t < 64) {
        unsigned v = relw[2 * t + 1];
        unsigned long long m = __ballot(v != 0u);
        if (t == 0) *flag = (m == 0ull) ? 1 : 0;
    }
    __shared__ float As[64][D + 1];
    __shared__ float Bs[64][D + 1];
    for (int i = t; i < 64 * D; i += 256) {
        int row = i / D, col = i - row * D;
        int ga = by * 64 + row;
        As[row][col] = (ga < R) ? Gs[ga * D + col] : 0.f;
        int gb = bx * 64 + row;
        Bs[row][col] = (gb < R) ? Gr[gb * D + col] : 0.f;
    }
    __syncthreads();
    const int ty = t >> 4, tx = t & 15;
    float acc[4][4];
#pragma unroll
    for (int i = 0; i < 4; i++)
#pragma unroll
        for (int j = 0; j < 4; j++) acc[i][j] = 0.f;
    for (int k = 0; k < D; k++) {
        float a[4], b[4];
#pragma unroll
        for (int i = 0; i < 4; i++) a[i] = As[4 * ty + i][k];
#pragma unroll
        for (int j = 0; j < 4; j++) b[j] = Bs[4 * tx + j][k];
#pragma unroll
        for (int i = 0; i < 4; i++)
#pragma unroll
            for (int j = 0; j < 4; j++) acc[i][j] += a[i] * b[j];
    }
#pragma unroll
    for (int i = 0; i < 4; i++) {
        int row = by * 64 + 4 * ty + i;
        if (row >= R) continue;
#pragma unroll
        for (int j = 0; j < 4; j++) {
            int col = bx * 64 + 4 * tx + j;
            if (col < R) table[row * R + col] = 1.0f / (1.0f + expf(-acc[i][j]));
        }
    }
}

// ---------------------------------------------------------------------------
// SORT PATH ------------------------------------------------------------------
// K3s: per 4096-edge block (512 thr x 8): batched unconditional loads
// (index-clamped so the compiler issues all of them back-to-back), gather
// table, write gates/recv, LDS multisplit by bucket=rv>>14, write bucket-
// sorted records + packed per-block offsets offtab[blk*NB+b]=off|(end<<16).
// Also zero-fills its slice of gbins (fused k_zero4). Deterministic.
__global__ __launch_bounds__(GST) void k_gate_sort(
    const void* __restrict__ rel, const void* __restrict__ pairs,
    const float* __restrict__ table, const int* __restrict__ flag,
    float* __restrict__ gates, int* __restrict__ recv32,
    unsigned* __restrict__ records, unsigned* __restrict__ offtab,
    unsigned* __restrict__ gz, int E, int store_recv) {
    __shared__ unsigned cnt[NB];
    __shared__ unsigned cursor[NB];
    __shared__ unsigned stage[EPB];
    __shared__ unsigned sh_carry, sh_total;
    const int tid = threadIdx.x;
    const int blk = blockIdx.x;
    const int base = blk * EPB;
    if (tid < NB) cnt[tid] = 0;
    if (gz) {  // fused gbins zeroing: one word/thread covers M across grid
        int zi = blk * GST + tid;
        if (zi < M) gz[zi] = 0u;
    }
    __syncthreads();

    const bool is64 = (*flag != 0);
    int idx[BT], rvv[BT];
    bool val[BT];
#pragma unroll
    for (int k = 0; k < BT; k++) val[k] = (base + k * GST + tid) < E;
    // Phase 0a: unconditional batched loads (clamped index; always in-bounds).
    if (is64) {
        ullx2 a[BT];
        ull b[BT];
#pragma unroll
        for (int k = 0; k < BT; k++) {
            int ec = min(base + k * GST + tid, E - 1);
            a[k] = __builtin_nontemporal_load((const ullx2*)rel + ec);
            b[k] = __builtin_nontemporal_load((const ull*)pairs + 2 * (size_t)ec + 1);
        }
#pragma unroll
        for (int k = 0; k < BT; k++) {
            idx[k] = (int)a[k].x * R + (int)a[k].y;
            rvv[k] = (int)b[k];
        }
    } else {
        intx2 a[BT];
        int b[BT];
#pragma unroll
        for (int k = 0; k < BT; k++) {
            int ec = min(base + k * GST + tid, E - 1);
            a[k] = __builtin_nontemporal_load((const intx2*)rel + ec);
            b[k] = __builtin_nontemporal_load((const int*)pairs + 2 * (size_t)ec + 1);
        }
#pragma unroll
        for (int k = 0; k < BT; k++) {
            idx[k] = a[k].x * R + a[k].y;
            rvv[k] = b[k];
        }
    }
    // Phase 0b: batched table gathers.
    float g[BT];
#pragma unroll
    for (int k = 0; k < BT; k++) g[k] = table[idx[k]];
    // Phase 0c: stores + rec pack + LDS bucket count.
    unsigned rec[BT];
#pragma unroll
    for (int k = 0; k < BT; k++) {
        int e = base + k * GST + tid;
        unsigned q = (unsigned)(g[k] * QSCALE + 0.5f);
        rec[k] = val[k] ? (((unsigned)rvv[k] << 11) | q) : 0xFFFFFFFFu;
        if (val[k]) {
            __builtin_nontemporal_store(g[k], gates + e);
            if (store_recv) __builtin_nontemporal_store(rvv[k], recv32 + e);
            atomicAdd(&cnt[(unsigned)rvv[k] >> BBITS], 1u);
        }
    }
    __syncthreads();
    // Scan 128 counts: per-wave shfl inclusive scan + carry.
    unsigned c = 0, inc = 0;
    if (tid < NB) {
        c = cnt[tid];
        inc = c;
#pragma unroll
        for (int d = 1; d < 64; d <<= 1) {
            unsigned n = __shfl_up(inc, d, 64);
            if ((tid & 63) >= d) inc += n;
        }
        if (tid == 63) sh_carry = inc;
    }
    __syncthreads();
    if (tid < NB) {
        if (tid >= 64) inc += sh_carry;
        unsigned exc = inc - c;
        cursor[tid] = exc;
        offtab[(size_t)blk * NB + tid] = exc | (inc << 16);
        if (tid == NB - 1) sh_total = inc;
    }
    __syncthreads();
    // Phase C: place records bucket-sorted into LDS staging.
#pragma unroll
    for (int k = 0; k < BT; k++) {
        if (rec[k] != 0xFFFFFFFFu) {
            unsigned b = rec[k] >> (11 + BBITS);
            unsigned pos = atomicAdd(&cursor[b], 1u);
            stage[pos] = rec[k];
        }
    }
    __syncthreads();
    // Phase D: coalesced flush to this block's global segment.
    unsigned total = sh_total;
    for (unsigned i = tid; i < total; i += GST)
        __builtin_nontemporal_store(stage[i], records + (size_t)blk * EPB + i);
}

// K4s: nsub blocks per bucket (blockIdx = sub*NB + b); contiguous chunk of
// block-segments per sub. Half-wave (32 lanes) per segment (avg run = 32).
// Packed offtab word prefetched one iteration ahead. nsub==1: write inv
// directly. nsub>1: deterministic u32 atomic flush to gbins (k_norm
// finalizes the reciprocal in-register).
__global__ __launch_bounds__(1024) void k_acc(const unsigned* __restrict__ records,
                                              const unsigned* __restrict__ offtab,
                                              float* __restrict__ inv,
                                              unsigned* __restrict__ gbins,
                                              int nblk, int nsub) {
    __shared__ unsigned bins[BINS];  // 64 KB -> 2 blocks/CU
    const int b = blockIdx.x & (NB - 1);
    const int sub = blockIdx.x >> 7;  // NB == 128
    for (int i = threadIdx.x; i < BINS; i += 1024) bins[i] = 0;
    __syncthreads();
    const int hw = threadIdx.x >> 5;   // 32 half-wave streams per block
    const int lane = threadIdx.x & 31;
    const int chunk = (nblk + nsub - 1) / nsub;
    const int s0 = sub * chunk;
    const int s1 = min(nblk, s0 + chunk);
    int s = s0 + hw;
    unsigned ot_next = (s < s1) ? offtab[(size_t)s * NB + b] : 0u;
    for (; s < s1; s += 32) {
        unsigned ot = ot_next;
        int sn = s + 32;
        if (sn < s1) ot_next = offtab[(size_t)sn * NB + b];  // prefetch, hides
        unsigned off = ot & 0xFFFFu;
        unsigned end = ot >> 16;
        const unsigned* seg = records + (size_t)s * EPB;
        for (unsigned j = off + lane; j < end; j += 32) {
            unsigned r2 = __builtin_nontemporal_load(seg + j);
            atomicAdd(&bins[(r2 >> 11) & (BINS - 1)], r2 & 2047u);
        }
    }
    __syncthreads();
    const int mbase = b << BBITS;
    if (nsub == 1) {
        for (int i = threadIdx.x; i < BINS; i += 1024) {
            int m = mbase + i;
            if (m < M) inv[m] = 1.0f / ((float)bins[i] * INV_QSCALE + 1e-8f);
        }
    } else {
        for (int i = threadIdx.x; i < BINS; i += 1024) {
            unsigned v = bins[i];
            int m = mbase + i;
            if (v && m < M)
                __hip_atomic_fetch_add(&gbins[m], v, __ATOMIC_RELAXED,
                                       __HIP_MEMORY_SCOPE_AGENT);
        }
    }
}

// ---------------------------------------------------------------------------
// FALLBACK PATH (small ws): round-4 atomic scheme -----------------------------
__global__ __launch_bounds__(256) void k_zero4(uintx4* __restrict__ p, int n4) {
    int i = blockIdx.x * 256 + threadIdx.x;
    if (i < n4) {
        uintx4 z = {0u, 0u, 0u, 0u};
        p[i] = z;
    }
}

__global__ __launch_bounds__(256) void k_gate_atomic(
    const void* __restrict__ rel, const void* __restrict__ pairs,
    const float* __restrict__ table, const int* __restrict__ flag,
    float* __restrict__ gates, unsigned* __restrict__ reps, int E) {
    const int tid = blockIdx.x * 256 + threadIdx.x;
    const int T = gridDim.x * 256;
    const bool is64 = (*flag != 0);
#pragma unroll
    for (int k = 0; k < BF; k++) {
        int e = tid + k * T;
        if (e < E) {
            int s, r, rv;
            if (is64) {
                ullx2 a = __builtin_nontemporal_load((const ullx2*)rel + e);
                ull b = __builtin_nontemporal_load((const ull*)pairs + 2 * e + 1);
                s = (int)a.x; r = (int)a.y; rv = (int)b;
            } else {
                intx2 a = __builtin_nontemporal_load((const intx2*)rel + e);
                int b = __builtin_nontemporal_load((const int*)pairs + 2 * e + 1);
                s = a.x; r = a.y; rv = b;
            }
            float g = table[s * R + r];
            __builtin_nontemporal_store(g, gates + e);
            unsigned q = (unsigned)(g * QSCALE + 0.5f);
            unsigned addend = q << ((rv & 1) << 4);
            __hip_atomic_fetch_add(&reps[rv >> 1], addend, __ATOMIC_RELAXED,
                                   __HIP_MEMORY_SCOPE_AGENT);
        }
    }
}

__global__ __launch_bounds__(256) void k_merge(const unsigned* __restrict__ reps,
                                               float* __restrict__ inv) {
    int i = blockIdx.x * 256 + threadIdx.x;
    if (i >= REP_WORDS) return;
    unsigned t = reps[i];
    floatx2 o;
    o.x = 1.0f / ((float)(t & 0xFFFFu) * INV_QSCALE + 1e-8f);
    o.y = 1.0f / ((float)(t >> 16) * INV_QSCALE + 1e-8f);
    ((floatx2*)inv)[i] = o;
}

// ---------------------------------------------------------------------------
// K5: out[e] = gate[e] * 1/denom[recv[e]].
// use_recv fast path: x4 vector loads, 16 edges/thread, 16 gathers in flight.
// mode==1: denom is gbins (u32 quantized sums) -> reciprocal in-register.
// mode==0: denom is inv (f32 reciprocals, from k_acc S=1 or fallback merge).
__global__ __launch_bounds__(256) void k_norm(const int* __restrict__ recv32,
                                              const void* __restrict__ pairs,
                                              const int* __restrict__ flag,
                                              const void* __restrict__ denom,
                                              float* __restrict__ out, int E,
                                              int use_recv, int mode) {
    const int gt = blockIdx.x * 256 + threadIdx.x;
    const int T = gridDim.x * 256;
    if (use_recv) {
        const unsigned* __restrict__ gb = (const unsigned*)denom;
        const float* __restrict__ iv_arr = (const float*)denom;
        intx4 rv4[NBV / 4];
        floatx4 gv4[NBV / 4];
        bool full[NBV / 4];
#pragma unroll
        for (int k = 0; k < NBV / 4; k++) {
            int c = gt + k * T;  // x4-chunk index
            full[k] = (4 * c + 4 <= E);
            if (full[k]) {
                rv4[k] = __builtin_nontemporal_load((const intx4*)recv32 + c);
                gv4[k] = __builtin_nontemporal_load((const floatx4*)out + c);
            }
        }
        float iv[NBV];
        if (mode) {
#pragma unroll
            for (int k = 0; k < NBV / 4; k++)
                if (full[k]) {
#pragma unroll
                    for (int j = 0; j < 4; j++) {
                        unsigned w = gb[rv4[k][j]];
                        iv[4 * k + j] = 1.0f / ((float)w * INV_QSCALE + 1e-8f);
                    }
                }
        } else {
#pragma unroll
            for (int k = 0; k < NBV / 4; k++)
                if (full[k]) {
#pragma unroll
                    for (int j = 0; j < 4; j++) iv[4 * k + j] = iv_arr[rv4[k][j]];
                }
        }
#pragma unroll
        for (int k = 0; k < NBV / 4; k++) {
            int c = gt + k * T;
            if (full[k]) {
                floatx4 o;
#pragma unroll
                for (int j = 0; j < 4; j++) o[j] = gv4[k][j] * iv[4 * k + j];
                __builtin_nontemporal_store(o, (floatx4*)out + c);
            } else {
                // tail: scalar
                for (int j = 0; j < 4; j++) {
                    int e = 4 * c + j;
                    if (e < E) {
                        int rv = recv32[e];
                        float ivs;
                        if (mode) {
                            unsigned w = gb[rv];
                            ivs = 1.0f / ((float)w * INV_QSCALE + 1e-8f);
                        } else {
                            ivs = iv_arr[rv];
                        }
                        out[e] = out[e] * ivs;
                    }
                }
            }
        }
    } else {
        // slow path: recv from pairs (scalar, BF ILP)
        const float* __restrict__ iv_arr = (const float*)denom;
        const unsigned* __restrict__ gb = (const unsigned*)denom;
        const bool is64 = (*flag != 0);
#pragma unroll
        for (int k = 0; k < BF * 2; k++) {
            int e = gt + k * T;
            if (e < E) {
                int rv = is64 ? (int)__builtin_nontemporal_load((const ull*)pairs + 2 * e + 1)
                              : __builtin_nontemporal_load((const int*)pairs + 2 * e + 1);
                float ivs;
                if (mode) {
                    unsigned w = gb[rv];
                    ivs = 1.0f / ((float)w * INV_QSCALE + 1e-8f);
                } else {
                    ivs = iv_arr[rv];
                }
                out[e] = out[e] * ivs;
            }
        }
    }
}

// ---------------------------------------------------------------------------
extern "C" void kernel_launch(void* const* d_in, const int* in_sizes, int n_in,
                              void* d_out, int out_size, void* d_ws, size_t ws_size,
                              hipStream_t stream) {
    const float* Gs = (const float*)d_in[0];
    const float* Gr = (const float*)d_in[1];
    const void* rel = d_in[2];
    const void* pairs = d_in[3];
    float* out = (float*)d_out;
    const int E = out_size;  // 16,000,000
    const int nblk = (E + EPB - 1) / EPB;

    // Workspace layout:
    //   flag    [0, 4)
    //   table   [4 KiB, +4 MiB)
    //   inv     [+4 MiB, +8 MiB)
    //   offtab  [+8 MiB, 4 MiB reserved)   nblk*NB u32 packed (~2 MiB)
    //   records [+4 MiB, nblk*EPB*4)       (~64 MB)  [sort path]
    //   recv32  [after records, 4*E)
    //   gbins   [after recv32, 4*M)        (~8 MB)   [k_acc split merge]
    char* ws = (char*)d_ws;
    int* flag = (int*)ws;
    size_t off_table = 4096;
    size_t off_inv = off_table + ((size_t)4 << 20);
    size_t off_off = off_inv + ((size_t)8 << 20);
    size_t off_recs = off_off + ((size_t)4 << 20);
    size_t off_recv = off_recs + (size_t)nblk * EPB * 4;
    float* table = (float*)(ws + off_table);
    float* inv = (float*)(ws + off_inv);
    unsigned* offtab = (unsigned*)(ws + off_off);
    unsigned* records = (unsigned*)(ws + off_recs);
    int* recv32 = (int*)(ws + off_recv);

    const int sort_ok = (ws_size >= off_recv) ? 1 : 0;
    const int store_recv = (ws_size >= off_recv + (size_t)E * 4) ? 1 : 0;
    size_t off_gb = off_recv + (store_recv ? (size_t)E * 4 : 0);
    const int have_gb = (ws_size >= off_gb + (size_t)M * 4) ? 1 : 0;
    unsigned* gbins = (unsigned*)(ws + off_gb);

    dim3 gt(16, 16);
    k_table<<<gt, 256, 0, stream>>>(Gs, Gr, table, (const unsigned*)rel, flag);

    if (sort_ok) {
        k_gate_sort<<<nblk, GST, 0, stream>>>(rel, pairs, table, flag, out, recv32,
                                              records, offtab,
                                              have_gb ? gbins : (unsigned*)nullptr,
                                              E, store_recv);
        const int S = have_gb ? NSUB : 1;
        k_acc<<<NB * S, 1024, 0, stream>>>(records, offtab, inv, gbins, nblk, S);
        const int ebv = (E + 256 * NBV - 1) / (256 * NBV);
        k_norm<<<ebv, 256, 0, stream>>>(recv32, pairs, flag,
                                        have_gb ? (const void*)gbins : (const void*)inv,
                                        out, E, store_recv, have_gb ? 1 : 0);
    } else {
        // Fallback: single-replica 16-bit global atomics (round-4 scheme).
        unsigned* reps = (unsigned*)(ws + off_off);
        k_zero4<<<(REP_WORDS / 4 + 255) / 256, 256, 0, stream>>>((uintx4*)reps,
                                                                 REP_WORDS / 4);
        const int eb = (E + 256 * BF - 1) / (256 * BF);
        k_gate_atomic<<<eb, 256, 0, stream>>>(rel, pairs, table, flag, out, reps, E);
        k_merge<<<(REP_WORDS + 255) / 256, 256, 0, stream>>>(reps, inv);
        const int ebv = (E + 256 * NBV - 1) / (256 * NBV);
        k_norm<<<ebv, 256, 0, stream>>>(recv32, pairs, flag, (const void*)inv,
                                        out, E, /*use_recv=*/0, /*mode=*/0);
    }
}